// Round 1
// baseline (351.763 us; speedup 1.0000x reference)
//
#include <hip/hip_runtime.h>
#include <math.h>

namespace {

constexpr int NB = 64, NT = 16384;
constexpr int NBT = NB * NT;              // 1,048,576 (b,t) pairs, 4 sources each
constexpr float VAD_TH  = 2.0f / 3.0f;
constexpr float AE_TH   = 30.0f;
constexpr float D2R     = 0.017453292519943295f;
constexpr float R2D     = 57.29577951308232f;
constexpr float CLIPV   = 0.99999f;

// ws layout (doubles): [0]=act_sum [1]=corr_sum [2]=ele_sum [3]=azi_sum [4]=aziele_sum

__global__ __launch_bounds__(256) void metric_main(
    const float* __restrict__ doa_gt, const float* __restrict__ vad_gt,
    const float* __restrict__ doa_est, const float* __restrict__ vad_est,
    double* __restrict__ ws)
{
    const int i = blockIdx.x * 256 + threadIdx.x;   // one (b,t) pair per thread

    float act = 0.f, corr = 0.f, s_ele = 0.f, s_azi = 0.f, s_ae = 0.f;

    // doa layout per (b,t): [2][4] floats = 32 B: ele[0..3], azi[0..3]
    const float4* dg = reinterpret_cast<const float4*>(doa_gt);
    const float4* de = reinterpret_cast<const float4*>(doa_est);
    float4 eg = dg[2 * i],     ag = dg[2 * i + 1];
    float4 ee = de[2 * i],     ae = de[2 * i + 1];
    float4 vg4 = reinterpret_cast<const float4*>(vad_gt)[i];
    float4 ve4 = reinterpret_cast<const float4*>(vad_est)[i];

    float egA[4] = {eg.x, eg.y, eg.z, eg.w}, agA[4] = {ag.x, ag.y, ag.z, ag.w};
    float eeA[4] = {ee.x, ee.y, ee.z, ee.w}, aeA[4] = {ae.x, ae.y, ae.z, ae.w};
    float vgA[4] = {vg4.x, vg4.y, vg4.z, vg4.w}, veA[4] = {ve4.x, ve4.y, ve4.z, ve4.w};

#pragma unroll
    for (int s = 0; s < 4; ++s) {
        float vg = (vgA[s] > VAD_TH) ? 1.f : 0.f;
        float ve = (veA[s] > VAD_TH) ? vg : 0.f;

        // floor-mod(d,360) for d in [-180,540], bit-identical to numpy's
        // fmod-then-adjust: negative branch is the same fp add, >=360 branch
        // is exact by Sterbenz.
        float d = aeA[s] - agA[s] + 180.f;
        d = (d < 0.f) ? d + 360.f : d;
        d = (d >= 360.f) ? d - 360.f : d;
        float azi_err = fabsf(d - 180.f);

        float ele_err = fabsf(eeA[s] - egA[s]);

        float gr = egA[s] * D2R;
        float er = eeA[s] * D2R;
        float ar = agA[s] * D2R - aeA[s] * D2R;   // matches ref: radians then subtract
        float aux = __cosf(gr) * __cosf(er) + __sinf(gr) * __sinf(er) * __cosf(ar);
        aux = fminf(fmaxf(aux, -CLIPV), CLIPV);
        float ae_err = acosf(aux) * R2D;          // acos >= 0, abs unnecessary

        act += vg;
        if (azi_err < AE_TH) corr += ve;
        s_ele += vg * ele_err;
        s_azi += vg * azi_err;
        s_ae  += vg * ae_err;
    }

    // wave64 shuffle reduction
#pragma unroll
    for (int off = 32; off > 0; off >>= 1) {
        act   += __shfl_down(act,   off, 64);
        corr  += __shfl_down(corr,  off, 64);
        s_ele += __shfl_down(s_ele, off, 64);
        s_azi += __shfl_down(s_azi, off, 64);
        s_ae  += __shfl_down(s_ae,  off, 64);
    }

    __shared__ float sm[4][5];
    const int wave = threadIdx.x >> 6;
    const int lane = threadIdx.x & 63;
    if (lane == 0) {
        sm[wave][0] = act;  sm[wave][1] = corr; sm[wave][2] = s_ele;
        sm[wave][3] = s_azi; sm[wave][4] = s_ae;
    }
    __syncthreads();
    if (threadIdx.x == 0) {
        double a = 0, c = 0, e = 0, z = 0, x = 0;
#pragma unroll
        for (int w = 0; w < 4; ++w) {
            a += (double)sm[w][0]; c += (double)sm[w][1]; e += (double)sm[w][2];
            z += (double)sm[w][3]; x += (double)sm[w][4];
        }
        atomicAdd(&ws[0], a);
        atomicAdd(&ws[1], c);
        atomicAdd(&ws[2], e);
        atomicAdd(&ws[3], z);
        atomicAdd(&ws[4], x);
    }
}

__global__ void metric_finalize(const double* __restrict__ ws, float* __restrict__ out)
{
    if (threadIdx.x == 0 && blockIdx.x == 0) {
        double act = ws[0];
        out[0] = (float)(ws[1] / act);   // ACC
        out[1] = (float)(ws[2] / act);   // MAE ele
        out[2] = (float)(ws[3] / act);   // MAE azi
        out[3] = (float)(ws[4] / act);   // MAE aziele
    }
}

} // namespace

extern "C" void kernel_launch(void* const* d_in, const int* in_sizes, int n_in,
                              void* d_out, int out_size, void* d_ws, size_t ws_size,
                              hipStream_t stream) {
    const float* doa_gt  = (const float*)d_in[0];
    const float* vad_gt  = (const float*)d_in[1];
    const float* doa_est = (const float*)d_in[2];
    const float* vad_est = (const float*)d_in[3];
    double* ws = (double*)d_ws;
    float* out = (float*)d_out;

    hipMemsetAsync(ws, 0, 5 * sizeof(double), stream);
    metric_main<<<NBT / 256, 256, 0, stream>>>(doa_gt, vad_gt, doa_est, vad_est, ws);
    metric_finalize<<<1, 64, 0, stream>>>(ws, out);
}

// Round 2
// 118.858 us; speedup vs baseline: 2.9595x; 2.9595x over previous
//
#include <hip/hip_runtime.h>
#include <math.h>

namespace {

constexpr int NB = 64, NT = 16384;
constexpr int NBT = NB * NT;              // 1,048,576 (b,t) pairs, 4 sources each
constexpr int NBLK   = 1024;              // blocks in main kernel
constexpr int NTHR   = 256;
constexpr int NPASS  = NBT / (NBLK * NTHR);   // 4 pairs per thread
constexpr float VAD_TH  = 2.0f / 3.0f;
constexpr float AE_TH   = 30.0f;
constexpr float D2R     = 0.017453292519943295f;
constexpr float R2D     = 57.29577951308232f;
constexpr float CLIPV   = 0.99999f;

// ws layout: float part[5][NBLK]  (SoA: metric-major, block-minor)
// metrics: 0=act 1=corr 2=ele 3=azi 4=aziele

__global__ __launch_bounds__(NTHR) void metric_main(
    const float* __restrict__ doa_gt, const float* __restrict__ vad_gt,
    const float* __restrict__ doa_est, const float* __restrict__ vad_est,
    float* __restrict__ part)
{
    const int gid = blockIdx.x * NTHR + threadIdx.x;

    float act = 0.f, corr = 0.f, s_ele = 0.f, s_azi = 0.f, s_ae = 0.f;

    const float4* dg = reinterpret_cast<const float4*>(doa_gt);
    const float4* de = reinterpret_cast<const float4*>(doa_est);
    const float4* vg_p = reinterpret_cast<const float4*>(vad_gt);
    const float4* ve_p = reinterpret_cast<const float4*>(vad_est);

#pragma unroll
    for (int p = 0; p < NPASS; ++p) {
        const int i = p * (NBLK * NTHR) + gid;   // (b,t) pair index, coalesced per pass

        // doa layout per (b,t): [2][4] floats = 32 B: ele[0..3] then azi[0..3]
        float4 eg = dg[2 * i], ag = dg[2 * i + 1];
        float4 ee = de[2 * i], ae = de[2 * i + 1];
        float4 vg4 = vg_p[i];
        float4 ve4 = ve_p[i];

        float egA[4] = {eg.x, eg.y, eg.z, eg.w}, agA[4] = {ag.x, ag.y, ag.z, ag.w};
        float eeA[4] = {ee.x, ee.y, ee.z, ee.w}, aeA[4] = {ae.x, ae.y, ae.z, ae.w};
        float vgA[4] = {vg4.x, vg4.y, vg4.z, vg4.w}, veA[4] = {ve4.x, ve4.y, ve4.z, ve4.w};

#pragma unroll
        for (int s = 0; s < 4; ++s) {
            float vg = (vgA[s] > VAD_TH) ? 1.f : 0.f;
            float ve = (veA[s] > VAD_TH) ? vg : 0.f;

            // floor-mod(d,360) for d in [-180,540]; bit-identical to numpy's
            // fmod-then-adjust (Sterbenz for the subtract branch).
            float d = aeA[s] - agA[s] + 180.f;
            d = (d < 0.f) ? d + 360.f : d;
            d = (d >= 360.f) ? d - 360.f : d;
            float azi_err = fabsf(d - 180.f);

            float ele_err = fabsf(eeA[s] - egA[s]);

            float gr = egA[s] * D2R;
            float er = eeA[s] * D2R;
            float ar = agA[s] * D2R - aeA[s] * D2R;
            float aux = __cosf(gr) * __cosf(er) + __sinf(gr) * __sinf(er) * __cosf(ar);
            aux = fminf(fmaxf(aux, -CLIPV), CLIPV);
            float ae_err = acosf(aux) * R2D;     // acos >= 0

            act += vg;
            if (azi_err < AE_TH) corr += ve;
            s_ele += vg * ele_err;
            s_azi += vg * azi_err;
            s_ae  += vg * ae_err;
        }
    }

    // wave64 shuffle reduction
#pragma unroll
    for (int off = 32; off > 0; off >>= 1) {
        act   += __shfl_down(act,   off, 64);
        corr  += __shfl_down(corr,  off, 64);
        s_ele += __shfl_down(s_ele, off, 64);
        s_azi += __shfl_down(s_azi, off, 64);
        s_ae  += __shfl_down(s_ae,  off, 64);
    }

    __shared__ float sm[4][5];
    const int wave = threadIdx.x >> 6;
    const int lane = threadIdx.x & 63;
    if (lane == 0) {
        sm[wave][0] = act;  sm[wave][1] = corr; sm[wave][2] = s_ele;
        sm[wave][3] = s_azi; sm[wave][4] = s_ae;
    }
    __syncthreads();
    if (threadIdx.x == 0) {
        float a = 0, c = 0, e = 0, z = 0, x = 0;
#pragma unroll
        for (int w = 0; w < 4; ++w) {
            a += sm[w][0]; c += sm[w][1]; e += sm[w][2];
            z += sm[w][3]; x += sm[w][4];
        }
        // one plain store per metric per block — no atomics, no line ping-pong
        part[0 * NBLK + blockIdx.x] = a;
        part[1 * NBLK + blockIdx.x] = c;
        part[2 * NBLK + blockIdx.x] = e;
        part[3 * NBLK + blockIdx.x] = z;
        part[4 * NBLK + blockIdx.x] = x;
    }
}

// One block: reduce 5 x NBLK partials in double, write 4 outputs.
__global__ __launch_bounds__(NTHR) void metric_finalize(
    const float* __restrict__ part, float* __restrict__ out)
{
    __shared__ double sm[4][5];
    const int t = threadIdx.x;
    double v[5];
#pragma unroll
    for (int m = 0; m < 5; ++m) {
        double acc = 0.0;
#pragma unroll
        for (int j = 0; j < NBLK / NTHR; ++j)
            acc += (double)part[m * NBLK + j * NTHR + t];
        v[m] = acc;
    }
#pragma unroll
    for (int off = 32; off > 0; off >>= 1)
#pragma unroll
        for (int m = 0; m < 5; ++m)
            v[m] += __shfl_down(v[m], off, 64);

    const int wave = t >> 6, lane = t & 63;
    if (lane == 0)
#pragma unroll
        for (int m = 0; m < 5; ++m) sm[wave][m] = v[m];
    __syncthreads();
    if (t == 0) {
        double tot[5];
#pragma unroll
        for (int m = 0; m < 5; ++m)
            tot[m] = sm[0][m] + sm[1][m] + sm[2][m] + sm[3][m];
        double act = tot[0];
        out[0] = (float)(tot[1] / act);   // ACC
        out[1] = (float)(tot[2] / act);   // MAE ele
        out[2] = (float)(tot[3] / act);   // MAE azi
        out[3] = (float)(tot[4] / act);   // MAE aziele
    }
}

} // namespace

extern "C" void kernel_launch(void* const* d_in, const int* in_sizes, int n_in,
                              void* d_out, int out_size, void* d_ws, size_t ws_size,
                              hipStream_t stream) {
    const float* doa_gt  = (const float*)d_in[0];
    const float* vad_gt  = (const float*)d_in[1];
    const float* doa_est = (const float*)d_in[2];
    const float* vad_est = (const float*)d_in[3];
    float* part = (float*)d_ws;          // 5 * NBLK floats = 20 KB
    float* out  = (float*)d_out;

    metric_main<<<NBLK, NTHR, 0, stream>>>(doa_gt, vad_gt, doa_est, vad_est, part);
    metric_finalize<<<1, NTHR, 0, stream>>>(part, out);
}